// Round 3
// baseline (437.423 us; speedup 1.0000x reference)
//
#include <hip/hip_runtime.h>

#define N_NODES 10000
#define N_EDGES 320000

// ---------------------------------------------------------------------------
// Graph preprocessing: deg/dinv + CSR-by-destination build
// ---------------------------------------------------------------------------

__global__ __launch_bounds__(256) void init_kernel(float* deg, int* counts, int* cursor, int n) {
    int i = blockIdx.x * 256 + threadIdx.x;
    if (i < n) { deg[i] = 1.0f; counts[i] = 0; cursor[i] = 0; }  // self-loop weight 1
}

__global__ __launch_bounds__(256) void deg_count_kernel(const int* __restrict__ col,
                                                        const float* __restrict__ ew,
                                                        float* __restrict__ deg,
                                                        int* __restrict__ counts, int e) {
    int i = blockIdx.x * 256 + threadIdx.x;
    if (i < e) {
        int c = col[i];
        atomicAdd(deg + c, ew[i]);
        atomicAdd(counts + c, 1);
    }
}

// Single-block 1024-thread exclusive scan, shuffle-based.
__global__ __launch_bounds__(1024) void scan_kernel(const int* __restrict__ counts,
                                                    int* __restrict__ ptr, int n) {
    __shared__ int wsum[16];
    __shared__ int woff[16];
    __shared__ int carry_s, tot_s;
    const int lane = threadIdx.x & 63;
    const int wid = threadIdx.x >> 6;
    if (threadIdx.x == 0) carry_s = 0;
    __syncthreads();
    for (int base = 0; base < n; base += 1024) {
        int i = base + (int)threadIdx.x;
        int v = (i < n) ? counts[i] : 0;
        int x = v;
#pragma unroll
        for (int off = 1; off < 64; off <<= 1) {
            int t = __shfl_up(x, off);
            if (lane >= off) x += t;
        }
        if (lane == 63) wsum[wid] = x;
        __syncthreads();
        if (wid == 0) {
            int s = (lane < 16) ? wsum[lane] : 0;
            int y = s;
#pragma unroll
            for (int off = 1; off < 16; off <<= 1) {
                int t = __shfl_up(y, off);
                if (lane >= off) y += t;
            }
            if (lane < 16) woff[lane] = y - s;
            if (lane == 15) tot_s = y;
        }
        __syncthreads();
        int carry = carry_s;
        if (i < n) ptr[i] = carry + woff[wid] + x - v;
        __syncthreads();
        if (threadIdx.x == 0) carry_s = carry + tot_s;
        __syncthreads();
    }
    if (threadIdx.x == 0) ptr[n] = carry_s;
}

__global__ __launch_bounds__(256) void dinv_kernel(const float* __restrict__ deg,
                                                   float* __restrict__ dinv, int n) {
    int i = blockIdx.x * 256 + threadIdx.x;
    if (i < n) {
        float d = deg[i];
        dinv[i] = (d > 0.0f) ? rsqrtf(d) : 0.0f;
    }
}

__global__ __launch_bounds__(256) void scatter_kernel(const int* __restrict__ row,
                                                      const int* __restrict__ col,
                                                      const float* __restrict__ ew,
                                                      const float* __restrict__ dinv,
                                                      const int* __restrict__ ptr,
                                                      int* __restrict__ cursor,
                                                      int* __restrict__ csr_src,
                                                      float* __restrict__ csr_w, int e) {
    int i = blockIdx.x * 256 + threadIdx.x;
    if (i < e) {
        int c = col[i], r = row[i];
        int pos = ptr[c] + atomicAdd(cursor + c, 1);
        csr_src[pos] = r;
        csr_w[pos] = dinv[r] * ew[i] * dinv[c];
    }
}

// ---------------------------------------------------------------------------
// bf16 split helpers (RNE)
// ---------------------------------------------------------------------------
__device__ __forceinline__ unsigned short f2bf_rne(float v) {
    unsigned int u = __float_as_uint(v);
    return (unsigned short)((u + 0x7FFFu + ((u >> 16) & 1u)) >> 16);
}
__device__ __forceinline__ float bf2f(unsigned short h) {
    return __uint_as_float(((unsigned int)h) << 16);
}

// ---------------------------------------------------------------------------
// Aggregation (pre-GEMM), split-bf16 output:
// acc[n] = dinv[n]^2 * x[n] + sum_in w * x[src]  (fp32), then hi/lo bf16 split.
// One block per node, F/4 threads, float4/thread, edge loop unrolled x4.
// ---------------------------------------------------------------------------
__global__ __launch_bounds__(128) void agg_pre_split_kernel(const float* __restrict__ x,
                                                            const int* __restrict__ ptr,
                                                            const int* __restrict__ csr_src,
                                                            const float* __restrict__ csr_w,
                                                            const float* __restrict__ dinv,
                                                            unsigned short* __restrict__ ohi,
                                                            unsigned short* __restrict__ olo,
                                                            int F) {
    const int node = blockIdx.x;
    const int f0 = (int)threadIdx.x * 4;
    const float di = dinv[node];
    const float si = di * di;
    float4 v = *(const float4*)(x + (size_t)node * F + f0);
    float ax = si * v.x, ay = si * v.y, az = si * v.z, aw = si * v.w;
    const int s = ptr[node], e = ptr[node + 1];
    int j = s;
    for (; j + 4 <= e; j += 4) {
        int s0 = csr_src[j], s1 = csr_src[j + 1], s2 = csr_src[j + 2], s3 = csr_src[j + 3];
        float w0 = csr_w[j], w1 = csr_w[j + 1], w2 = csr_w[j + 2], w3 = csr_w[j + 3];
        float4 g0 = *(const float4*)(x + (size_t)s0 * F + f0);
        float4 g1 = *(const float4*)(x + (size_t)s1 * F + f0);
        float4 g2 = *(const float4*)(x + (size_t)s2 * F + f0);
        float4 g3 = *(const float4*)(x + (size_t)s3 * F + f0);
        ax += w0 * g0.x + w1 * g1.x + w2 * g2.x + w3 * g3.x;
        ay += w0 * g0.y + w1 * g1.y + w2 * g2.y + w3 * g3.y;
        az += w0 * g0.z + w1 * g1.z + w2 * g2.z + w3 * g3.z;
        aw += w0 * g0.w + w1 * g1.w + w2 * g2.w + w3 * g3.w;
    }
    for (; j < e; ++j) {
        int sj = csr_src[j];
        float w = csr_w[j];
        float4 g = *(const float4*)(x + (size_t)sj * F + f0);
        ax += w * g.x; ay += w * g.y; az += w * g.z; aw += w * g.w;
    }
    float a4[4] = {ax, ay, az, aw};
    ushort4 hv, lv;
    unsigned short* hp = (unsigned short*)&hv;
    unsigned short* lp = (unsigned short*)&lv;
#pragma unroll
    for (int q = 0; q < 4; ++q) {
        unsigned short h = f2bf_rne(a4[q]);
        float r = a4[q] - bf2f(h);
        hp[q] = h;
        lp[q] = f2bf_rne(r);
    }
    *(ushort4*)(ohi + (size_t)node * F + f0) = hv;
    *(ushort4*)(olo + (size_t)node * F + f0) = lv;
}

// Convert+transpose weights: W [K][N] fp32 -> Wt_hi/Wt_lo [N][K] bf16.
__global__ __launch_bounds__(256) void convert_wt_kernel(const float* __restrict__ W,
                                                         unsigned short* __restrict__ hi,
                                                         unsigned short* __restrict__ lo,
                                                         int K, int N) {
    int idx = blockIdx.x * 256 + threadIdx.x;
    if (idx >= K * N) return;
    int k = idx / N, n = idx - k * N;
    float v = W[idx];
    unsigned short h = f2bf_rne(v);
    float r = v - bf2f(h);
    hi[(size_t)n * K + k] = h;
    lo[(size_t)n * K + k] = f2bf_rne(r);
}

// ---------------------------------------------------------------------------
// Split-bf16 MFMA GEMM + bias (+relu):
//   C[M,N] = (Ahi+Alo)[M,K] @ (Bhi+Blo)[K,N] + bias   (drop lo*lo term)
// B supplied TRANSPOSED as Bt[N][K].  Tile 128(M) x 64(N), BK=32, 256 threads,
// 4 waves each computing 64m x 32n via 4x2 grid of 16x16x32 MFMAs (x3 split).
// Verified layouts (learn_hip m89/m91/m120):
//   A-frag: lane L holds A[m=L&15][k=(L>>4)*8+j]
//   B-frag: lane L holds B[k=(L>>4)*8+j][n=L&15]
//   C/D   : lane L reg r -> row=(L>>4)*4+r, col=L&15
// ---------------------------------------------------------------------------
typedef short bf16x8 __attribute__((ext_vector_type(8)));
typedef float f32x4 __attribute__((ext_vector_type(4)));

#define TM 128
#define TN 64
#define BK 32
#define SA 40   // padded k-stride (bf16 elems): 2-way-max LDS bank aliasing (free)

__global__ __launch_bounds__(256) void gemm_mfma_kernel(const unsigned short* __restrict__ Ahi,
                                                        const unsigned short* __restrict__ Alo,
                                                        const unsigned short* __restrict__ Bthi,
                                                        const unsigned short* __restrict__ Btlo,
                                                        const float* __restrict__ bias,
                                                        float* __restrict__ C,
                                                        int M, int K, int N, int relu) {
    __shared__ unsigned short lA[2 * TM * SA];   // [hi|lo][m][k]
    __shared__ unsigned short lB[2 * TN * SA];   // [hi|lo][n][k]
    const int t = (int)threadIdx.x;
    const int bm = blockIdx.y * TM;
    const int bn = blockIdx.x * TN;
    const int lane = t & 63;
    const int wave = t >> 6;
    const int wm = (wave & 1) * 64;      // wave's m-offset in tile
    const int wn = (wave >> 1) * 32;     // wave's n-offset in tile
    const int quad = lane >> 4;
    const int lr = lane & 15;

    // staging indices: A tile has 128 rows x 4 kvecs (8 bf16 each) = 512 vecs -> 2/thread
    const int ar0 = t >> 2, ak0 = (t & 3) * 8;          // vec t
    const int ar1 = (t + 256) >> 2;                     // vec t+256 (same kvec pattern)
    // B tile: 64 rows x 4 kvecs = 256 vecs -> 1/thread
    const int br = t >> 2, bk = (t & 3) * 8;

    f32x4 acc[4][2];
    const f32x4 zero4 = {0.f, 0.f, 0.f, 0.f};
#pragma unroll
    for (int i = 0; i < 4; ++i)
#pragma unroll
        for (int j = 0; j < 2; ++j) acc[i][j] = zero4;

    uint4 ra_hi[2], ra_lo[2], rb_hi, rb_lo;
    const uint4 z16 = {0u, 0u, 0u, 0u};

    const int KT = K >> 5;   // BK=32

    // prologue: load tile 0 into regs
    {
        const int k0 = 0;
        int r0 = bm + ar0, r1 = bm + ar1;
        ra_hi[0] = (r0 < M) ? *(const uint4*)(Ahi + (size_t)r0 * K + k0 + ak0) : z16;
        ra_lo[0] = (r0 < M) ? *(const uint4*)(Alo + (size_t)r0 * K + k0 + ak0) : z16;
        ra_hi[1] = (r1 < M) ? *(const uint4*)(Ahi + (size_t)r1 * K + k0 + ak0) : z16;
        ra_lo[1] = (r1 < M) ? *(const uint4*)(Alo + (size_t)r1 * K + k0 + ak0) : z16;
        rb_hi = *(const uint4*)(Bthi + (size_t)(bn + br) * K + k0 + bk);
        rb_lo = *(const uint4*)(Btlo + (size_t)(bn + br) * K + k0 + bk);
    }

    for (int kt = 0; kt < KT; ++kt) {
        // stage regs -> LDS
        *(uint4*)(&lA[ar0 * SA + ak0]) = ra_hi[0];
        *(uint4*)(&lA[TM * SA + ar0 * SA + ak0]) = ra_lo[0];
        *(uint4*)(&lA[ar1 * SA + ak0]) = ra_hi[1];
        *(uint4*)(&lA[TM * SA + ar1 * SA + ak0]) = ra_lo[1];
        *(uint4*)(&lB[br * SA + bk]) = rb_hi;
        *(uint4*)(&lB[TN * SA + br * SA + bk]) = rb_lo;
        __syncthreads();

        // prefetch next tile into regs (hidden behind MFMA compute)
        if (kt + 1 < KT) {
            const int k0 = (kt + 1) * BK;
            int r0 = bm + ar0, r1 = bm + ar1;
            ra_hi[0] = (r0 < M) ? *(const uint4*)(Ahi + (size_t)r0 * K + k0 + ak0) : z16;
            ra_lo[0] = (r0 < M) ? *(const uint4*)(Alo + (size_t)r0 * K + k0 + ak0) : z16;
            ra_hi[1] = (r1 < M) ? *(const uint4*)(Ahi + (size_t)r1 * K + k0 + ak0) : z16;
            ra_lo[1] = (r1 < M) ? *(const uint4*)(Alo + (size_t)r1 * K + k0 + ak0) : z16;
            rb_hi = *(const uint4*)(Bthi + (size_t)(bn + br) * K + k0 + bk);
            rb_lo = *(const uint4*)(Btlo + (size_t)(bn + br) * K + k0 + bk);
        }

        // fragments
        bf16x8 ah[4], al[4], bh[2], bl[2];
#pragma unroll
        for (int i = 0; i < 4; ++i) {
            int off = (wm + i * 16 + lr) * SA + quad * 8;
            ah[i] = *(const bf16x8*)(&lA[off]);
            al[i] = *(const bf16x8*)(&lA[TM * SA + off]);
        }
#pragma unroll
        for (int j = 0; j < 2; ++j) {
            int off = (wn + j * 16 + lr) * SA + quad * 8;
            bh[j] = *(const bf16x8*)(&lB[off]);
            bl[j] = *(const bf16x8*)(&lB[TN * SA + off]);
        }
#pragma unroll
        for (int i = 0; i < 4; ++i)
#pragma unroll
            for (int j = 0; j < 2; ++j) {
                acc[i][j] = __builtin_amdgcn_mfma_f32_16x16x32_bf16(ah[i], bh[j], acc[i][j], 0, 0, 0);
                acc[i][j] = __builtin_amdgcn_mfma_f32_16x16x32_bf16(ah[i], bl[j], acc[i][j], 0, 0, 0);
                acc[i][j] = __builtin_amdgcn_mfma_f32_16x16x32_bf16(al[i], bh[j], acc[i][j], 0, 0, 0);
            }
        __syncthreads();
    }

    // epilogue: bias (+relu), store fp32
    float bcol[2];
#pragma unroll
    for (int j = 0; j < 2; ++j) bcol[j] = bias[bn + wn + j * 16 + lr];
#pragma unroll
    for (int i = 0; i < 4; ++i) {
#pragma unroll
        for (int j = 0; j < 2; ++j) {
#pragma unroll
            for (int r = 0; r < 4; ++r) {
                int m = bm + wm + i * 16 + quad * 4 + r;
                if (m < M) {
                    float vv = acc[i][j][r] + bcol[j];
                    if (relu) vv = fmaxf(vv, 0.f);
                    C[(size_t)m * N + bn + wn + j * 16 + lr] = vv;
                }
            }
        }
    }
}

// ---------------------------------------------------------------------------
// GEMM for layer 3: N=8, K=768.  One 64-lane wave per output row (fp32).
// ---------------------------------------------------------------------------
__global__ __launch_bounds__(64) void gemm_n8_kernel(const float* __restrict__ A,
                                                     const float* __restrict__ B,
                                                     float* __restrict__ C, int K) {
    int m = blockIdx.x;
    int lane = threadIdx.x;
    const float* a = A + (size_t)m * K;
    float acc[8] = {};
    for (int k = lane; k < K; k += 64) {
        float av = a[k];
        float4 b0 = *(const float4*)(B + (size_t)k * 8);
        float4 b1 = *(const float4*)(B + (size_t)k * 8 + 4);
        acc[0] += av * b0.x; acc[1] += av * b0.y; acc[2] += av * b0.z; acc[3] += av * b0.w;
        acc[4] += av * b1.x; acc[5] += av * b1.y; acc[6] += av * b1.z; acc[7] += av * b1.w;
    }
#pragma unroll
    for (int off = 32; off > 0; off >>= 1) {
#pragma unroll
        for (int i = 0; i < 8; ++i) acc[i] += __shfl_down(acc[i], off);
    }
    if (lane == 0) {
#pragma unroll
        for (int i = 0; i < 8; ++i) C[(size_t)m * 8 + i] = acc[i];
    }
}

// Aggregation for fout=8 (final layer, +bias): one wave per node, lanes split edges.
__global__ __launch_bounds__(64) void agg8_kernel(const float* __restrict__ xw,
                                                  const int* __restrict__ ptr,
                                                  const int* __restrict__ csr_src,
                                                  const float* __restrict__ csr_w,
                                                  const float* __restrict__ dinv,
                                                  const float* __restrict__ bias,
                                                  float* __restrict__ out) {
    int node = blockIdx.x;
    int lane = threadIdx.x;
    float acc[8] = {};
    int s = ptr[node], e = ptr[node + 1];
    for (int j = s + lane; j < e; j += 64) {
        int src = csr_src[j];
        float w = csr_w[j];
        float4 g0 = *(const float4*)(xw + (size_t)src * 8);
        float4 g1 = *(const float4*)(xw + (size_t)src * 8 + 4);
        acc[0] += w * g0.x; acc[1] += w * g0.y; acc[2] += w * g0.z; acc[3] += w * g0.w;
        acc[4] += w * g1.x; acc[5] += w * g1.y; acc[6] += w * g1.z; acc[7] += w * g1.w;
    }
#pragma unroll
    for (int off = 32; off > 0; off >>= 1) {
#pragma unroll
        for (int i = 0; i < 8; ++i) acc[i] += __shfl_down(acc[i], off);
    }
    if (lane == 0) {
        float di = dinv[node];
        float si = di * di;
#pragma unroll
        for (int i = 0; i < 8; ++i)
            out[(size_t)node * 8 + i] = acc[i] + si * xw[(size_t)node * 8 + i] + bias[i];
    }
}

// ---------------------------------------------------------------------------

extern "C" void kernel_launch(void* const* d_in, const int* in_sizes, int n_in,
                              void* d_out, int out_size, void* d_ws, size_t ws_size,
                              hipStream_t stream) {
    const int N = N_NODES, E = N_EDGES;
    const float* x   = (const float*)d_in[0];
    const int*   ei  = (const int*)d_in[1];   // [2, E] (row=source, col=target)
    const float* ew  = (const float*)d_in[2];
    const float* W1  = (const float*)d_in[3];
    const float* b1  = (const float*)d_in[4];
    const float* W2  = (const float*)d_in[5];
    const float* b2  = (const float*)d_in[6];
    const float* W3  = (const float*)d_in[7];
    const float* b3  = (const float*)d_in[8];
    float* out = (float*)d_out;

    const int* row = ei;        // source
    const int* col = ei + E;    // target

    // workspace layout (256B-aligned); ~57 MB total
    char* ws = (char*)d_ws;
    size_t off = 0;
    auto alloc = [&](size_t bytes) {
        void* p = ws + off;
        off += (bytes + 255) & ~(size_t)255;
        return p;
    };
    float*          deg     = (float*)alloc((size_t)N * 4);
    float*          dinv    = (float*)alloc((size_t)N * 4);
    int*            counts  = (int*)alloc((size_t)N * 4);
    int*            cursor  = (int*)alloc((size_t)N * 4);
    int*            col_ptr = (int*)alloc((size_t)(N + 1) * 4);
    int*            csr_src = (int*)alloc((size_t)E * 4);
    float*          csr_w   = (float*)alloc((size_t)E * 4);
    float*          bufF    = (float*)alloc((size_t)N * 768 * 4);     // fp32 activations (reused)
    unsigned short* Ahi     = (unsigned short*)alloc((size_t)N * 512 * 2);
    unsigned short* Alo     = (unsigned short*)alloc((size_t)N * 512 * 2);
    unsigned short* W1thi   = (unsigned short*)alloc((size_t)512 * 256 * 2);
    unsigned short* W1tlo   = (unsigned short*)alloc((size_t)512 * 256 * 2);
    unsigned short* W2thi   = (unsigned short*)alloc((size_t)768 * 512 * 2);
    unsigned short* W2tlo   = (unsigned short*)alloc((size_t)768 * 512 * 2);
    float*          xw8     = (float*)alloc((size_t)N * 8 * 4);
    (void)ws_size;

    int nb_nodes = (N + 255) / 256;
    int nb_edges = (E + 255) / 256;

    // --- graph preprocessing (once; shared by all 3 layers) ---
    init_kernel<<<nb_nodes, 256, 0, stream>>>(deg, counts, cursor, N);
    deg_count_kernel<<<nb_edges, 256, 0, stream>>>(col, ew, deg, counts, E);
    scan_kernel<<<1, 1024, 0, stream>>>(counts, col_ptr, N);
    dinv_kernel<<<nb_nodes, 256, 0, stream>>>(deg, dinv, N);
    scatter_kernel<<<nb_edges, 256, 0, stream>>>(row, col, ew, dinv, col_ptr, cursor,
                                                 csr_src, csr_w, E);

    // --- weight conversion (bf16 hi/lo, transposed) ---
    convert_wt_kernel<<<(256 * 512 + 255) / 256, 256, 0, stream>>>(W1, W1thi, W1tlo, 256, 512);
    convert_wt_kernel<<<(512 * 768 + 255) / 256, 256, 0, stream>>>(W2, W2thi, W2tlo, 512, 768);

    // --- layer 1: agg(256, split) -> mfma gemm 256->512 (+b1, relu) ---
    agg_pre_split_kernel<<<N, 64, 0, stream>>>(x, col_ptr, csr_src, csr_w, dinv, Ahi, Alo, 256);
    {
        dim3 grid(512 / TN, (N + TM - 1) / TM);
        gemm_mfma_kernel<<<grid, 256, 0, stream>>>(Ahi, Alo, W1thi, W1tlo, b1, bufF,
                                                   N, 256, 512, 1);
    }
    // --- layer 2: agg(512, split) -> mfma gemm 512->768 (+b2, relu) ---
    agg_pre_split_kernel<<<N, 128, 0, stream>>>(bufF, col_ptr, csr_src, csr_w, dinv, Ahi, Alo, 512);
    {
        dim3 grid(768 / TN, (N + TM - 1) / TM);
        gemm_mfma_kernel<<<grid, 256, 0, stream>>>(Ahi, Alo, W2thi, W2tlo, b2, bufF,
                                                   N, 512, 768, 0 /* relu below? no: */ + 1);
    }
    // --- layer 3: gemm 768->8 -> agg8 (+b3) ---
    gemm_n8_kernel<<<N, 64, 0, stream>>>(bufF, W3, xw8, 768);
    agg8_kernel<<<N, 64, 0, stream>>>(xw8, col_ptr, csr_src, csr_w, dinv, b3, out);

    (void)out_size; (void)n_in; (void)in_sizes;
}

// Round 4
// 355.792 us; speedup vs baseline: 1.2294x; 1.2294x over previous
//
#include <hip/hip_runtime.h>

#define N_NODES 10000
#define N_EDGES 320000

// ---------------------------------------------------------------------------
// Graph preprocessing: deg/dinv + CSR-by-destination build
// ---------------------------------------------------------------------------

__global__ __launch_bounds__(256) void init_kernel(float* deg, int* counts, int* cursor, int n) {
    int i = blockIdx.x * 256 + threadIdx.x;
    if (i < n) { deg[i] = 1.0f; counts[i] = 0; cursor[i] = 0; }  // self-loop weight 1
}

__global__ __launch_bounds__(256) void deg_count_kernel(const int* __restrict__ col,
                                                        const float* __restrict__ ew,
                                                        float* __restrict__ deg,
                                                        int* __restrict__ counts, int e) {
    int i = blockIdx.x * 256 + threadIdx.x;
    if (i < e) {
        int c = col[i];
        atomicAdd(deg + c, ew[i]);
        atomicAdd(counts + c, 1);
    }
}

// Single-block 1024-thread exclusive scan, shuffle-based.
__global__ __launch_bounds__(1024) void scan_kernel(const int* __restrict__ counts,
                                                    int* __restrict__ ptr, int n) {
    __shared__ int wsum[16];
    __shared__ int woff[16];
    __shared__ int carry_s, tot_s;
    const int lane = threadIdx.x & 63;
    const int wid = threadIdx.x >> 6;
    if (threadIdx.x == 0) carry_s = 0;
    __syncthreads();
    for (int base = 0; base < n; base += 1024) {
        int i = base + (int)threadIdx.x;
        int v = (i < n) ? counts[i] : 0;
        int x = v;
#pragma unroll
        for (int off = 1; off < 64; off <<= 1) {
            int t = __shfl_up(x, off);
            if (lane >= off) x += t;
        }
        if (lane == 63) wsum[wid] = x;
        __syncthreads();
        if (wid == 0) {
            int s = (lane < 16) ? wsum[lane] : 0;
            int y = s;
#pragma unroll
            for (int off = 1; off < 16; off <<= 1) {
                int t = __shfl_up(y, off);
                if (lane >= off) y += t;
            }
            if (lane < 16) woff[lane] = y - s;
            if (lane == 15) tot_s = y;
        }
        __syncthreads();
        int carry = carry_s;
        if (i < n) ptr[i] = carry + woff[wid] + x - v;
        __syncthreads();
        if (threadIdx.x == 0) carry_s = carry + tot_s;
        __syncthreads();
    }
    if (threadIdx.x == 0) ptr[n] = carry_s;
}

__global__ __launch_bounds__(256) void dinv_kernel(const float* __restrict__ deg,
                                                   float* __restrict__ dinv, int n) {
    int i = blockIdx.x * 256 + threadIdx.x;
    if (i < n) {
        float d = deg[i];
        dinv[i] = (d > 0.0f) ? rsqrtf(d) : 0.0f;
    }
}

__global__ __launch_bounds__(256) void scatter_kernel(const int* __restrict__ row,
                                                      const int* __restrict__ col,
                                                      const float* __restrict__ ew,
                                                      const float* __restrict__ dinv,
                                                      const int* __restrict__ ptr,
                                                      int* __restrict__ cursor,
                                                      int* __restrict__ csr_src,
                                                      float* __restrict__ csr_w, int e) {
    int i = blockIdx.x * 256 + threadIdx.x;
    if (i < e) {
        int c = col[i], r = row[i];
        int pos = ptr[c] + atomicAdd(cursor + c, 1);
        csr_src[pos] = r;
        csr_w[pos] = dinv[r] * ew[i] * dinv[c];
    }
}

// ---------------------------------------------------------------------------
// bf16 split helpers (RNE)
// ---------------------------------------------------------------------------
__device__ __forceinline__ unsigned short f2bf_rne(float v) {
    unsigned int u = __float_as_uint(v);
    return (unsigned short)((u + 0x7FFFu + ((u >> 16) & 1u)) >> 16);
}
__device__ __forceinline__ float bf2f(unsigned short h) {
    return __uint_as_float(((unsigned int)h) << 16);
}

// ---------------------------------------------------------------------------
// Aggregation (pre-GEMM), split-bf16 output:
// acc[n] = dinv[n]^2 * x[n] + sum_in w * x[src]  (fp32), then hi/lo bf16 split.
// ---------------------------------------------------------------------------
__global__ __launch_bounds__(128) void agg_pre_split_kernel(const float* __restrict__ x,
                                                            const int* __restrict__ ptr,
                                                            const int* __restrict__ csr_src,
                                                            const float* __restrict__ csr_w,
                                                            const float* __restrict__ dinv,
                                                            unsigned short* __restrict__ ohi,
                                                            unsigned short* __restrict__ olo,
                                                            int F) {
    const int node = blockIdx.x;
    const int f0 = (int)threadIdx.x * 4;
    const float di = dinv[node];
    const float si = di * di;
    float4 v = *(const float4*)(x + (size_t)node * F + f0);
    float ax = si * v.x, ay = si * v.y, az = si * v.z, aw = si * v.w;
    const int s = ptr[node], e = ptr[node + 1];
    int j = s;
    for (; j + 4 <= e; j += 4) {
        int s0 = csr_src[j], s1 = csr_src[j + 1], s2 = csr_src[j + 2], s3 = csr_src[j + 3];
        float w0 = csr_w[j], w1 = csr_w[j + 1], w2 = csr_w[j + 2], w3 = csr_w[j + 3];
        float4 g0 = *(const float4*)(x + (size_t)s0 * F + f0);
        float4 g1 = *(const float4*)(x + (size_t)s1 * F + f0);
        float4 g2 = *(const float4*)(x + (size_t)s2 * F + f0);
        float4 g3 = *(const float4*)(x + (size_t)s3 * F + f0);
        ax += w0 * g0.x + w1 * g1.x + w2 * g2.x + w3 * g3.x;
        ay += w0 * g0.y + w1 * g1.y + w2 * g2.y + w3 * g3.y;
        az += w0 * g0.z + w1 * g1.z + w2 * g2.z + w3 * g3.z;
        aw += w0 * g0.w + w1 * g1.w + w2 * g2.w + w3 * g3.w;
    }
    for (; j < e; ++j) {
        int sj = csr_src[j];
        float w = csr_w[j];
        float4 g = *(const float4*)(x + (size_t)sj * F + f0);
        ax += w * g.x; ay += w * g.y; az += w * g.z; aw += w * g.w;
    }
    float a4[4] = {ax, ay, az, aw};
    ushort4 hv, lv;
    unsigned short* hp = (unsigned short*)&hv;
    unsigned short* lp = (unsigned short*)&lv;
#pragma unroll
    for (int q = 0; q < 4; ++q) {
        unsigned short h = f2bf_rne(a4[q]);
        float r = a4[q] - bf2f(h);
        hp[q] = h;
        lp[q] = f2bf_rne(r);
    }
    *(ushort4*)(ohi + (size_t)node * F + f0) = hv;
    *(ushort4*)(olo + (size_t)node * F + f0) = lv;
}

// Convert+transpose weights: W [K][N] fp32 -> Wt_hi/Wt_lo [N][K] bf16.
__global__ __launch_bounds__(256) void convert_wt_kernel(const float* __restrict__ W,
                                                         unsigned short* __restrict__ hi,
                                                         unsigned short* __restrict__ lo,
                                                         int K, int N) {
    int idx = blockIdx.x * 256 + threadIdx.x;
    if (idx >= K * N) return;
    int k = idx / N, n = idx - k * N;
    float v = W[idx];
    unsigned short h = f2bf_rne(v);
    float r = v - bf2f(h);
    hi[(size_t)n * K + k] = h;
    lo[(size_t)n * K + k] = f2bf_rne(r);
}

// ---------------------------------------------------------------------------
// Split-bf16 MFMA GEMM + bias (+relu), async global->LDS staging.
//   C[M,N] = (Ahi+Alo)[M,K] @ (Bhi+Blo)[K,N] + bias   (lo*lo dropped)
// B supplied transposed as Bt[N][K]; A padded to a multiple of 128 rows
// (pad rows garbage, their outputs discarded).
// Tile 128m x 64n, BK=32, 256 threads = 4 waves of 64m x 32n.
// LDS layout: unpadded [row][32 bf16] blocks, XOR-swizzled chunks:
//   chunk c of row r stored at slot c ^ ((r>>1)&3)  -> 2-way bank alias (free).
// global_load_lds writes wave-contiguous 1024B (16 rows) per issue.
// ---------------------------------------------------------------------------
typedef short bf16x8 __attribute__((ext_vector_type(8)));
typedef float f32x4 __attribute__((ext_vector_type(4)));

#define TM 128
#define TN 64
#define BK 32
#define LDS_A_HI 0
#define LDS_A_LO 8192
#define LDS_B_HI 16384
#define LDS_B_LO 20480
#define LDS_BUF  24576

__device__ __forceinline__ void async16(const unsigned short* g, unsigned char* l) {
    __builtin_amdgcn_global_load_lds(
        (const __attribute__((address_space(1))) unsigned int*)g,
        (__attribute__((address_space(3))) unsigned int*)l, 16, 0, 0);
}

__global__ __launch_bounds__(256, 2) void gemm_mfma_kernel(
        const unsigned short* __restrict__ Ahi,
        const unsigned short* __restrict__ Alo,
        const unsigned short* __restrict__ Bthi,
        const unsigned short* __restrict__ Btlo,
        const float* __restrict__ bias,
        float* __restrict__ C,
        int M, int K, int N, int relu) {
    __shared__ unsigned char lds[2 * LDS_BUF];
    const int t = (int)threadIdx.x;
    const int bm = blockIdx.y * TM;
    const int bn = blockIdx.x * TN;
    const int lane = t & 63;
    const int wave = t >> 6;
    const int wm = (wave & 1) * 64;
    const int wn = (wave >> 1) * 32;

    // ---- staging geometry (per lane) ----
    const int slr = lane >> 2;                       // 0..15 local row
    const int scc = (lane & 3) ^ ((slr >> 1) & 3);   // swizzled global chunk
    const int abi0 = wave * 2, abi1 = wave * 2 + 1;  // A 16-row block ids (0..7)
    // global element bases (advance by k0 each tile); A is row-padded -> no guards
    const unsigned short* gA0h = Ahi + (size_t)(bm + abi0 * 16 + slr) * K + scc * 8;
    const unsigned short* gA1h = Ahi + (size_t)(bm + abi1 * 16 + slr) * K + scc * 8;
    const unsigned short* gA0l = Alo + (size_t)(bm + abi0 * 16 + slr) * K + scc * 8;
    const unsigned short* gA1l = Alo + (size_t)(bm + abi1 * 16 + slr) * K + scc * 8;
    const unsigned short* gBh  = Bthi + (size_t)(bn + wave * 16 + slr) * K + scc * 8;
    const unsigned short* gBl  = Btlo + (size_t)(bn + wave * 16 + slr) * K + scc * 8;

    // ---- fragment read geometry ----
    const int quad = lane >> 4;
    const int lr16 = lane & 15;
    const int fs = (quad ^ ((lr16 >> 1) & 3)) * 16;  // swizzled slot byte offset

    f32x4 acc[4][2];
    const f32x4 zero4 = {0.f, 0.f, 0.f, 0.f};
#pragma unroll
    for (int i = 0; i < 4; ++i)
#pragma unroll
        for (int j = 0; j < 2; ++j) acc[i][j] = zero4;

    const int KT = K / BK;

    auto stage = [&](int kt, int buf) {
        const int k0 = kt * BK;
        unsigned char* b = &lds[buf * LDS_BUF];
        async16(gA0h + k0, b + LDS_A_HI + abi0 * 1024);
        async16(gA1h + k0, b + LDS_A_HI + abi1 * 1024);
        async16(gA0l + k0, b + LDS_A_LO + abi0 * 1024);
        async16(gA1l + k0, b + LDS_A_LO + abi1 * 1024);
        async16(gBh + k0, b + LDS_B_HI + wave * 1024);
        async16(gBl + k0, b + LDS_B_LO + wave * 1024);
    };

    stage(0, 0);
    __syncthreads();

    for (int kt = 0; kt < KT; ++kt) {
        const int buf = kt & 1;
        if (kt + 1 < KT) stage(kt + 1, buf ^ 1);   // async, drains at barrier below

        unsigned char* b = &lds[buf * LDS_BUF];
        bf16x8 ah[4], al[4], bh[2], bl[2];
#pragma unroll
        for (int i = 0; i < 4; ++i) {
            int ro = (wm + i * 16 + lr16) * 64 + fs;
            ah[i] = *(const bf16x8*)(b + LDS_A_HI + ro);
            al[i] = *(const bf16x8*)(b + LDS_A_LO + ro);
        }
#pragma unroll
        for (int j = 0; j < 2; ++j) {
            int ro = (wn + j * 16 + lr16) * 64 + fs;
            bh[j] = *(const bf16x8*)(b + LDS_B_HI + ro);
            bl[j] = *(const bf16x8*)(b + LDS_B_LO + ro);
        }
#pragma unroll
        for (int i = 0; i < 4; ++i)
#pragma unroll
            for (int j = 0; j < 2; ++j) {
                acc[i][j] = __builtin_amdgcn_mfma_f32_16x16x32_bf16(ah[i], bh[j], acc[i][j], 0, 0, 0);
                acc[i][j] = __builtin_amdgcn_mfma_f32_16x16x32_bf16(ah[i], bl[j], acc[i][j], 0, 0, 0);
                acc[i][j] = __builtin_amdgcn_mfma_f32_16x16x32_bf16(al[i], bh[j], acc[i][j], 0, 0, 0);
            }
        __syncthreads();
    }

    // epilogue: bias (+relu), store fp32
    float bcol[2];
#pragma unroll
    for (int j = 0; j < 2; ++j) bcol[j] = bias[bn + wn + j * 16 + lr16];
#pragma unroll
    for (int i = 0; i < 4; ++i) {
#pragma unroll
        for (int j = 0; j < 2; ++j) {
#pragma unroll
            for (int r = 0; r < 4; ++r) {
                int m = bm + wm + i * 16 + quad * 4 + r;
                if (m < M) {
                    float vv = acc[i][j][r] + bcol[j];
                    if (relu) vv = fmaxf(vv, 0.f);
                    C[(size_t)m * N + bn + wn + j * 16 + lr16] = vv;
                }
            }
        }
    }
}

// ---------------------------------------------------------------------------
// GEMM for layer 3: N=8, K=768.  One 64-lane wave per output row (fp32).
// ---------------------------------------------------------------------------
__global__ __launch_bounds__(64) void gemm_n8_kernel(const float* __restrict__ A,
                                                     const float* __restrict__ B,
                                                     float* __restrict__ C, int K) {
    int m = blockIdx.x;
    int lane = threadIdx.x;
    const float* a = A + (size_t)m * K;
    float acc[8] = {};
    for (int k = lane; k < K; k += 64) {
        float av = a[k];
        float4 b0 = *(const float4*)(B + (size_t)k * 8);
        float4 b1 = *(const float4*)(B + (size_t)k * 8 + 4);
        acc[0] += av * b0.x; acc[1] += av * b0.y; acc[2] += av * b0.z; acc[3] += av * b0.w;
        acc[4] += av * b1.x; acc[5] += av * b1.y; acc[6] += av * b1.z; acc[7] += av * b1.w;
    }
#pragma unroll
    for (int off = 32; off > 0; off >>= 1) {
#pragma unroll
        for (int i = 0; i < 8; ++i) acc[i] += __shfl_down(acc[i], off);
    }
    if (lane == 0) {
#pragma unroll
        for (int i = 0; i < 8; ++i) C[(size_t)m * 8 + i] = acc[i];
    }
}

// Aggregation for fout=8 (final layer, +bias): one wave per node, lanes split edges.
__global__ __launch_bounds__(64) void agg8_kernel(const float* __restrict__ xw,
                                                  const int* __restrict__ ptr,
                                                  const int* __restrict__ csr_src,
                                                  const float* __restrict__ csr_w,
                                                  const float* __restrict__ dinv,
                                                  const float* __restrict__ bias,
                                                  float* __restrict__ out) {
    int node = blockIdx.x;
    int lane = threadIdx.x;
    float acc[8] = {};
    int s = ptr[node], e = ptr[node + 1];
    for (int j = s + lane; j < e; j += 64) {
        int src = csr_src[j];
        float w = csr_w[j];
        float4 g0 = *(const float4*)(xw + (size_t)src * 8);
        float4 g1 = *(const float4*)(xw + (size_t)src * 8 + 4);
        acc[0] += w * g0.x; acc[1] += w * g0.y; acc[2] += w * g0.z; acc[3] += w * g0.w;
        acc[4] += w * g1.x; acc[5] += w * g1.y; acc[6] += w * g1.z; acc[7] += w * g1.w;
    }
#pragma unroll
    for (int off = 32; off > 0; off >>= 1) {
#pragma unroll
        for (int i = 0; i < 8; ++i) acc[i] += __shfl_down(acc[i], off);
    }
    if (lane == 0) {
        float di = dinv[node];
        float si = di * di;
#pragma unroll
        for (int i = 0; i < 8; ++i)
            out[(size_t)node * 8 + i] = acc[i] + si * xw[(size_t)node * 8 + i] + bias[i];
    }
}

// ---------------------------------------------------------------------------

extern "C" void kernel_launch(void* const* d_in, const int* in_sizes, int n_in,
                              void* d_out, int out_size, void* d_ws, size_t ws_size,
                              hipStream_t stream) {
    const int N = N_NODES, E = N_EDGES;
    const int N_PAD = ((N + TM - 1) / TM) * TM;   // 10112: pad A rows for guardless staging
    const float* x   = (const float*)d_in[0];
    const int*   ei  = (const int*)d_in[1];   // [2, E] (row=source, col=target)
    const float* ew  = (const float*)d_in[2];
    const float* W1  = (const float*)d_in[3];
    const float* b1  = (const float*)d_in[4];
    const float* W2  = (const float*)d_in[5];
    const float* b2  = (const float*)d_in[6];
    const float* W3  = (const float*)d_in[7];
    const float* b3  = (const float*)d_in[8];
    float* out = (float*)d_out;

    const int* row = ei;        // source
    const int* col = ei + E;    // target

    // workspace layout (256B-aligned); ~58 MB total
    char* ws = (char*)d_ws;
    size_t off = 0;
    auto alloc = [&](size_t bytes) {
        void* p = ws + off;
        off += (bytes + 255) & ~(size_t)255;
        return p;
    };
    float*          deg     = (float*)alloc((size_t)N * 4);
    float*          dinv    = (float*)alloc((size_t)N * 4);
    int*            counts  = (int*)alloc((size_t)N * 4);
    int*            cursor  = (int*)alloc((size_t)N * 4);
    int*            col_ptr = (int*)alloc((size_t)(N + 1) * 4);
    int*            csr_src = (int*)alloc((size_t)E * 4);
    float*          csr_w   = (float*)alloc((size_t)E * 4);
    float*          bufF    = (float*)alloc((size_t)N * 768 * 4);       // fp32 activations
    unsigned short* Ahi     = (unsigned short*)alloc((size_t)N_PAD * 512 * 2);
    unsigned short* Alo     = (unsigned short*)alloc((size_t)N_PAD * 512 * 2);
    unsigned short* W1thi   = (unsigned short*)alloc((size_t)512 * 256 * 2);
    unsigned short* W1tlo   = (unsigned short*)alloc((size_t)512 * 256 * 2);
    unsigned short* W2thi   = (unsigned short*)alloc((size_t)768 * 512 * 2);
    unsigned short* W2tlo   = (unsigned short*)alloc((size_t)768 * 512 * 2);
    float*          xw8     = (float*)alloc((size_t)N * 8 * 4);
    (void)ws_size;

    int nb_nodes = (N + 255) / 256;
    int nb_edges = (E + 255) / 256;

    // --- graph preprocessing (once; shared by all 3 layers) ---
    init_kernel<<<nb_nodes, 256, 0, stream>>>(deg, counts, cursor, N);
    deg_count_kernel<<<nb_edges, 256, 0, stream>>>(col, ew, deg, counts, E);
    scan_kernel<<<1, 1024, 0, stream>>>(counts, col_ptr, N);
    dinv_kernel<<<nb_nodes, 256, 0, stream>>>(deg, dinv, N);
    scatter_kernel<<<nb_edges, 256, 0, stream>>>(row, col, ew, dinv, col_ptr, cursor,
                                                 csr_src, csr_w, E);

    // --- weight conversion (bf16 hi/lo, transposed) ---
    convert_wt_kernel<<<(256 * 512 + 255) / 256, 256, 0, stream>>>(W1, W1thi, W1tlo, 256, 512);
    convert_wt_kernel<<<(512 * 768 + 255) / 256, 256, 0, stream>>>(W2, W2thi, W2tlo, 512, 768);

    // --- layer 1: agg(256, split) -> mfma gemm 256->512 (+b1, relu) ---
    agg_pre_split_kernel<<<N, 64, 0, stream>>>(x, col_ptr, csr_src, csr_w, dinv, Ahi, Alo, 256);
    {
        dim3 grid(512 / TN, N_PAD / TM);
        gemm_mfma_kernel<<<grid, 256, 0, stream>>>(Ahi, Alo, W1thi, W1tlo, b1, bufF,
                                                   N, 256, 512, 1);
    }
    // --- layer 2: agg(512, split) -> mfma gemm 512->768 (+b2, relu) ---
    agg_pre_split_kernel<<<N, 128, 0, stream>>>(bufF, col_ptr, csr_src, csr_w, dinv, Ahi, Alo, 512);
    {
        dim3 grid(768 / TN, N_PAD / TM);
        gemm_mfma_kernel<<<grid, 256, 0, stream>>>(Ahi, Alo, W2thi, W2tlo, b2, bufF,
                                                   N, 512, 768, 1);
    }
    // --- layer 3: gemm 768->8 -> agg8 (+b3) ---
    gemm_n8_kernel<<<N, 64, 0, stream>>>(bufF, W3, xw8, 768);
    agg8_kernel<<<N, 64, 0, stream>>>(xw8, col_ptr, csr_src, csr_w, dinv, b3, out);

    (void)out_size; (void)n_in; (void)in_sizes;
}

// Round 5
// 308.788 us; speedup vs baseline: 1.4166x; 1.1522x over previous
//
#include <hip/hip_runtime.h>

#define N_NODES 10000
#define N_EDGES 320000

// ---------------------------------------------------------------------------
// Graph preprocessing: deg/dinv + CSR-by-destination build
// ---------------------------------------------------------------------------

__global__ __launch_bounds__(256) void init_kernel(float* deg, int* counts, int* cursor, int n) {
    int i = blockIdx.x * 256 + threadIdx.x;
    if (i < n) { deg[i] = 1.0f; counts[i] = 0; cursor[i] = 0; }  // self-loop weight 1
}

__global__ __launch_bounds__(256) void deg_count_kernel(const int* __restrict__ col,
                                                        const float* __restrict__ ew,
                                                        float* __restrict__ deg,
                                                        int* __restrict__ counts, int e) {
    int i = blockIdx.x * 256 + threadIdx.x;
    if (i < e) {
        int c = col[i];
        atomicAdd(deg + c, ew[i]);
        atomicAdd(counts + c, 1);
    }
}

// Single-block 1024-thread exclusive scan, shuffle-based.
__global__ __launch_bounds__(1024) void scan_kernel(const int* __restrict__ counts,
                                                    int* __restrict__ ptr, int n) {
    __shared__ int wsum[16];
    __shared__ int woff[16];
    __shared__ int carry_s, tot_s;
    const int lane = threadIdx.x & 63;
    const int wid = threadIdx.x >> 6;
    if (threadIdx.x == 0) carry_s = 0;
    __syncthreads();
    for (int base = 0; base < n; base += 1024) {
        int i = base + (int)threadIdx.x;
        int v = (i < n) ? counts[i] : 0;
        int x = v;
#pragma unroll
        for (int off = 1; off < 64; off <<= 1) {
            int t = __shfl_up(x, off);
            if (lane >= off) x += t;
        }
        if (lane == 63) wsum[wid] = x;
        __syncthreads();
        if (wid == 0) {
            int s = (lane < 16) ? wsum[lane] : 0;
            int y = s;
#pragma unroll
            for (int off = 1; off < 16; off <<= 1) {
                int t = __shfl_up(y, off);
                if (lane >= off) y += t;
            }
            if (lane < 16) woff[lane] = y - s;
            if (lane == 15) tot_s = y;
        }
        __syncthreads();
        int carry = carry_s;
        if (i < n) ptr[i] = carry + woff[wid] + x - v;
        __syncthreads();
        if (threadIdx.x == 0) carry_s = carry + tot_s;
        __syncthreads();
    }
    if (threadIdx.x == 0) ptr[n] = carry_s;
}

__global__ __launch_bounds__(256) void dinv_kernel(const float* __restrict__ deg,
                                                   float* __restrict__ dinv, int n) {
    int i = blockIdx.x * 256 + threadIdx.x;
    if (i < n) {
        float d = deg[i];
        dinv[i] = (d > 0.0f) ? rsqrtf(d) : 0.0f;
    }
}

__global__ __launch_bounds__(256) void scatter_kernel(const int* __restrict__ row,
                                                      const int* __restrict__ col,
                                                      const float* __restrict__ ew,
                                                      const float* __restrict__ dinv,
                                                      const int* __restrict__ ptr,
                                                      int* __restrict__ cursor,
                                                      int* __restrict__ csr_src,
                                                      float* __restrict__ csr_w, int e) {
    int i = blockIdx.x * 256 + threadIdx.x;
    if (i < e) {
        int c = col[i], r = row[i];
        int pos = ptr[c] + atomicAdd(cursor + c, 1);
        csr_src[pos] = r;
        csr_w[pos] = dinv[r] * ew[i] * dinv[c];
    }
}

// ---------------------------------------------------------------------------
// bf16 split helpers (RNE)
// ---------------------------------------------------------------------------
__device__ __forceinline__ unsigned short f2bf_rne(float v) {
    unsigned int u = __float_as_uint(v);
    return (unsigned short)((u + 0x7FFFu + ((u >> 16) & 1u)) >> 16);
}
__device__ __forceinline__ float bf2f(unsigned short h) {
    return __uint_as_float(((unsigned int)h) << 16);
}

// ---------------------------------------------------------------------------
// XCD-sliced aggregation with split-bf16 output:
//   acc[n,f] = dinv[n]^2 * x[n,f] + sum_in w * x[src,f]   (fp32 accumulate)
// One 64-lane wave per (node, 64-feature slice); lane = one feature.
// slice = blockIdx.x & slice_mask: with round-robin blockIdx->XCD dispatch,
// each XCD touches ONE 2.56 MB activation slab -> gathers stay L2-resident.
// ---------------------------------------------------------------------------
__global__ __launch_bounds__(64) void agg_slice_kernel(const float* __restrict__ x,
                                                       const int* __restrict__ ptr,
                                                       const int* __restrict__ csr_src,
                                                       const float* __restrict__ csr_w,
                                                       const float* __restrict__ dinv,
                                                       unsigned short* __restrict__ ohi,
                                                       unsigned short* __restrict__ olo,
                                                       int F, int slice_mask, int slice_shift) {
    const int b = blockIdx.x;
    const int slice = b & slice_mask;
    const int node = b >> slice_shift;
    const int f = slice * 64 + (int)threadIdx.x;
    const float di = dinv[node];
    const float si = di * di;
    float acc = si * x[(size_t)node * F + f];
    const int s = ptr[node], e = ptr[node + 1];
    int j = s;
    for (; j + 4 <= e; j += 4) {
        int s0 = csr_src[j], s1 = csr_src[j + 1], s2 = csr_src[j + 2], s3 = csr_src[j + 3];
        float w0 = csr_w[j], w1 = csr_w[j + 1], w2 = csr_w[j + 2], w3 = csr_w[j + 3];
        float g0 = x[(size_t)s0 * F + f];
        float g1 = x[(size_t)s1 * F + f];
        float g2 = x[(size_t)s2 * F + f];
        float g3 = x[(size_t)s3 * F + f];
        acc += w0 * g0 + w1 * g1 + w2 * g2 + w3 * g3;
    }
    for (; j < e; ++j) {
        acc += csr_w[j] * x[(size_t)csr_src[j] * F + f];
    }
    unsigned short h = f2bf_rne(acc);
    float r = acc - bf2f(h);
    ohi[(size_t)node * F + f] = h;
    olo[(size_t)node * F + f] = f2bf_rne(r);
}

// Convert+transpose weights: W [K][N] fp32 -> Wt_hi/Wt_lo [N][K] bf16.
__global__ __launch_bounds__(256) void convert_wt_kernel(const float* __restrict__ W,
                                                         unsigned short* __restrict__ hi,
                                                         unsigned short* __restrict__ lo,
                                                         int K, int N) {
    int idx = blockIdx.x * 256 + threadIdx.x;
    if (idx >= K * N) return;
    int k = idx / N, n = idx - k * N;
    float v = W[idx];
    unsigned short h = f2bf_rne(v);
    float r = v - bf2f(h);
    hi[(size_t)n * K + k] = h;
    lo[(size_t)n * K + k] = f2bf_rne(r);
}

// ---------------------------------------------------------------------------
// Split-bf16 MFMA GEMM + bias (+relu), async global->LDS staging.
//   C[M,N] = (Ahi+Alo)[M,K] @ (Bhi+Blo)[K,N] + bias   (lo*lo dropped)
// B supplied transposed as Bt[N][K]; A padded to a multiple of 128 rows.
// Tile 128m x 64n, BK=32, 256 threads = 4 waves of 64m x 32n.
// LDS: unpadded [row][32 bf16] blocks, XOR chunk swizzle (2-way alias, free).
// ---------------------------------------------------------------------------
typedef short bf16x8 __attribute__((ext_vector_type(8)));
typedef float f32x4 __attribute__((ext_vector_type(4)));

#define TM 128
#define TN 64
#define BK 32
#define LDS_A_HI 0
#define LDS_A_LO 8192
#define LDS_B_HI 16384
#define LDS_B_LO 20480
#define LDS_BUF  24576

__device__ __forceinline__ void async16(const unsigned short* g, unsigned char* l) {
    __builtin_amdgcn_global_load_lds(
        (const __attribute__((address_space(1))) unsigned int*)g,
        (__attribute__((address_space(3))) unsigned int*)l, 16, 0, 0);
}

__global__ __launch_bounds__(256, 2) void gemm_mfma_kernel(
        const unsigned short* __restrict__ Ahi,
        const unsigned short* __restrict__ Alo,
        const unsigned short* __restrict__ Bthi,
        const unsigned short* __restrict__ Btlo,
        const float* __restrict__ bias,
        float* __restrict__ C,
        int M, int K, int N, int relu) {
    __shared__ unsigned char lds[2 * LDS_BUF];
    const int t = (int)threadIdx.x;
    const int bm = blockIdx.y * TM;
    const int bn = blockIdx.x * TN;
    const int lane = t & 63;
    const int wave = t >> 6;
    const int wm = (wave & 1) * 64;
    const int wn = (wave >> 1) * 32;

    // ---- staging geometry (per lane) ----
    const int slr = lane >> 2;                       // 0..15 local row
    const int scc = (lane & 3) ^ ((slr >> 1) & 3);   // swizzled global chunk
    const int abi0 = wave * 2, abi1 = wave * 2 + 1;  // A 16-row block ids
    const unsigned short* gA0h = Ahi + (size_t)(bm + abi0 * 16 + slr) * K + scc * 8;
    const unsigned short* gA1h = Ahi + (size_t)(bm + abi1 * 16 + slr) * K + scc * 8;
    const unsigned short* gA0l = Alo + (size_t)(bm + abi0 * 16 + slr) * K + scc * 8;
    const unsigned short* gA1l = Alo + (size_t)(bm + abi1 * 16 + slr) * K + scc * 8;
    const unsigned short* gBh  = Bthi + (size_t)(bn + wave * 16 + slr) * K + scc * 8;
    const unsigned short* gBl  = Btlo + (size_t)(bn + wave * 16 + slr) * K + scc * 8;

    // ---- fragment read geometry ----
    const int quad = lane >> 4;
    const int lr16 = lane & 15;
    const int fs = (quad ^ ((lr16 >> 1) & 3)) * 16;  // swizzled slot byte offset

    f32x4 acc[4][2];
    const f32x4 zero4 = {0.f, 0.f, 0.f, 0.f};
#pragma unroll
    for (int i = 0; i < 4; ++i)
#pragma unroll
        for (int j = 0; j < 2; ++j) acc[i][j] = zero4;

    const int KT = K / BK;

    auto stage = [&](int kt, int buf) {
        const int k0 = kt * BK;
        unsigned char* b = &lds[buf * LDS_BUF];
        async16(gA0h + k0, b + LDS_A_HI + abi0 * 1024);
        async16(gA1h + k0, b + LDS_A_HI + abi1 * 1024);
        async16(gA0l + k0, b + LDS_A_LO + abi0 * 1024);
        async16(gA1l + k0, b + LDS_A_LO + abi1 * 1024);
        async16(gBh + k0, b + LDS_B_HI + wave * 1024);
        async16(gBl + k0, b + LDS_B_LO + wave * 1024);
    };

    stage(0, 0);
    __syncthreads();

    for (int kt = 0; kt < KT; ++kt) {
        const int buf = kt & 1;
        if (kt + 1 < KT) stage(kt + 1, buf ^ 1);   // async, drains at barrier below

        unsigned char* b = &lds[buf * LDS_BUF];
        bf16x8 ah[4], al[4], bh[2], bl[2];
#pragma unroll
        for (int i = 0; i < 4; ++i) {
            int ro = (wm + i * 16 + lr16) * 64 + fs;
            ah[i] = *(const bf16x8*)(b + LDS_A_HI + ro);
            al[i] = *(const bf16x8*)(b + LDS_A_LO + ro);
        }
#pragma unroll
        for (int j = 0; j < 2; ++j) {
            int ro = (wn + j * 16 + lr16) * 64 + fs;
            bh[j] = *(const bf16x8*)(b + LDS_B_HI + ro);
            bl[j] = *(const bf16x8*)(b + LDS_B_LO + ro);
        }
#pragma unroll
        for (int i = 0; i < 4; ++i)
#pragma unroll
            for (int j = 0; j < 2; ++j) {
                acc[i][j] = __builtin_amdgcn_mfma_f32_16x16x32_bf16(ah[i], bh[j], acc[i][j], 0, 0, 0);
                acc[i][j] = __builtin_amdgcn_mfma_f32_16x16x32_bf16(ah[i], bl[j], acc[i][j], 0, 0, 0);
                acc[i][j] = __builtin_amdgcn_mfma_f32_16x16x32_bf16(al[i], bh[j], acc[i][j], 0, 0, 0);
            }
        __syncthreads();
    }

    // epilogue: bias (+relu), store fp32
    float bcol[2];
#pragma unroll
    for (int j = 0; j < 2; ++j) bcol[j] = bias[bn + wn + j * 16 + lr16];
#pragma unroll
    for (int i = 0; i < 4; ++i) {
#pragma unroll
        for (int j = 0; j < 2; ++j) {
#pragma unroll
            for (int r = 0; r < 4; ++r) {
                int m = bm + wm + i * 16 + quad * 4 + r;
                if (m < M) {
                    float vv = acc[i][j][r] + bcol[j];
                    if (relu) vv = fmaxf(vv, 0.f);
                    C[(size_t)m * N + bn + wn + j * 16 + lr16] = vv;
                }
            }
        }
    }
}

// ---------------------------------------------------------------------------
// GEMM for layer 3: N=8, K=768.  One 64-lane wave per output row (fp32).
// ---------------------------------------------------------------------------
__global__ __launch_bounds__(64) void gemm_n8_kernel(const float* __restrict__ A,
                                                     const float* __restrict__ B,
                                                     float* __restrict__ C, int K) {
    int m = blockIdx.x;
    int lane = threadIdx.x;
    const float* a = A + (size_t)m * K;
    float acc[8] = {};
    for (int k = lane; k < K; k += 64) {
        float av = a[k];
        float4 b0 = *(const float4*)(B + (size_t)k * 8);
        float4 b1 = *(const float4*)(B + (size_t)k * 8 + 4);
        acc[0] += av * b0.x; acc[1] += av * b0.y; acc[2] += av * b0.z; acc[3] += av * b0.w;
        acc[4] += av * b1.x; acc[5] += av * b1.y; acc[6] += av * b1.z; acc[7] += av * b1.w;
    }
#pragma unroll
    for (int off = 32; off > 0; off >>= 1) {
#pragma unroll
        for (int i = 0; i < 8; ++i) acc[i] += __shfl_down(acc[i], off);
    }
    if (lane == 0) {
#pragma unroll
        for (int i = 0; i < 8; ++i) C[(size_t)m * 8 + i] = acc[i];
    }
}

// Aggregation for fout=8 (final layer, +bias): one wave per node, lanes split edges.
__global__ __launch_bounds__(64) void agg8_kernel(const float* __restrict__ xw,
                                                  const int* __restrict__ ptr,
                                                  const int* __restrict__ csr_src,
                                                  const float* __restrict__ csr_w,
                                                  const float* __restrict__ dinv,
                                                  const float* __restrict__ bias,
                                                  float* __restrict__ out) {
    int node = blockIdx.x;
    int lane = threadIdx.x;
    float acc[8] = {};
    int s = ptr[node], e = ptr[node + 1];
    for (int j = s + lane; j < e; j += 64) {
        int src = csr_src[j];
        float w = csr_w[j];
        float4 g0 = *(const float4*)(xw + (size_t)src * 8);
        float4 g1 = *(const float4*)(xw + (size_t)src * 8 + 4);
        acc[0] += w * g0.x; acc[1] += w * g0.y; acc[2] += w * g0.z; acc[3] += w * g0.w;
        acc[4] += w * g1.x; acc[5] += w * g1.y; acc[6] += w * g1.z; acc[7] += w * g1.w;
    }
#pragma unroll
    for (int off = 32; off > 0; off >>= 1) {
#pragma unroll
        for (int i = 0; i < 8; ++i) acc[i] += __shfl_down(acc[i], off);
    }
    if (lane == 0) {
        float di = dinv[node];
        float si = di * di;
#pragma unroll
        for (int i = 0; i < 8; ++i)
            out[(size_t)node * 8 + i] = acc[i] + si * xw[(size_t)node * 8 + i] + bias[i];
    }
}

// ---------------------------------------------------------------------------

extern "C" void kernel_launch(void* const* d_in, const int* in_sizes, int n_in,
                              void* d_out, int out_size, void* d_ws, size_t ws_size,
                              hipStream_t stream) {
    const int N = N_NODES, E = N_EDGES;
    const int N_PAD = ((N + TM - 1) / TM) * TM;   // 10112: pad A rows for guardless staging
    const float* x   = (const float*)d_in[0];
    const int*   ei  = (const int*)d_in[1];   // [2, E] (row=source, col=target)
    const float* ew  = (const float*)d_in[2];
    const float* W1  = (const float*)d_in[3];
    const float* b1  = (const float*)d_in[4];
    const float* W2  = (const float*)d_in[5];
    const float* b2  = (const float*)d_in[6];
    const float* W3  = (const float*)d_in[7];
    const float* b3  = (const float*)d_in[8];
    float* out = (float*)d_out;

    const int* row = ei;        // source
    const int* col = ei + E;    // target

    // workspace layout (256B-aligned); ~58 MB total
    char* ws = (char*)d_ws;
    size_t off = 0;
    auto alloc = [&](size_t bytes) {
        void* p = ws + off;
        off += (bytes + 255) & ~(size_t)255;
        return p;
    };
    float*          deg     = (float*)alloc((size_t)N * 4);
    float*          dinv    = (float*)alloc((size_t)N * 4);
    int*            counts  = (int*)alloc((size_t)N * 4);
    int*            cursor  = (int*)alloc((size_t)N * 4);
    int*            col_ptr = (int*)alloc((size_t)(N + 1) * 4);
    int*            csr_src = (int*)alloc((size_t)E * 4);
    float*          csr_w   = (float*)alloc((size_t)E * 4);
    float*          bufF    = (float*)alloc((size_t)N * 768 * 4);       // fp32 activations
    unsigned short* Ahi     = (unsigned short*)alloc((size_t)N_PAD * 512 * 2);
    unsigned short* Alo     = (unsigned short*)alloc((size_t)N_PAD * 512 * 2);
    unsigned short* W1thi   = (unsigned short*)alloc((size_t)512 * 256 * 2);
    unsigned short* W1tlo   = (unsigned short*)alloc((size_t)512 * 256 * 2);
    unsigned short* W2thi   = (unsigned short*)alloc((size_t)768 * 512 * 2);
    unsigned short* W2tlo   = (unsigned short*)alloc((size_t)768 * 512 * 2);
    float*          xw8     = (float*)alloc((size_t)N * 8 * 4);
    (void)ws_size;

    int nb_nodes = (N + 255) / 256;
    int nb_edges = (E + 255) / 256;

    // --- graph preprocessing (once; shared by all 3 layers) ---
    init_kernel<<<nb_nodes, 256, 0, stream>>>(deg, counts, cursor, N);
    deg_count_kernel<<<nb_edges, 256, 0, stream>>>(col, ew, deg, counts, E);
    scan_kernel<<<1, 1024, 0, stream>>>(counts, col_ptr, N);
    dinv_kernel<<<nb_nodes, 256, 0, stream>>>(deg, dinv, N);
    scatter_kernel<<<nb_edges, 256, 0, stream>>>(row, col, ew, dinv, col_ptr, cursor,
                                                 csr_src, csr_w, E);

    // --- weight conversion (bf16 hi/lo, transposed) ---
    convert_wt_kernel<<<(256 * 512 + 255) / 256, 256, 0, stream>>>(W1, W1thi, W1tlo, 256, 512);
    convert_wt_kernel<<<(512 * 768 + 255) / 256, 256, 0, stream>>>(W2, W2thi, W2tlo, 512, 768);

    // --- layer 1: agg(256, 4 slices) -> mfma gemm 256->512 (+b1, relu) ---
    agg_slice_kernel<<<N * 4, 64, 0, stream>>>(x, col_ptr, csr_src, csr_w, dinv,
                                               Ahi, Alo, 256, 3, 2);
    {
        dim3 grid(512 / TN, N_PAD / TM);
        gemm_mfma_kernel<<<grid, 256, 0, stream>>>(Ahi, Alo, W1thi, W1tlo, b1, bufF,
                                                   N, 256, 512, 1);
    }
    // --- layer 2: agg(512, 8 slices) -> mfma gemm 512->768 (+b2, relu) ---
    agg_slice_kernel<<<N * 8, 64, 0, stream>>>(bufF, col_ptr, csr_src, csr_w, dinv,
                                               Ahi, Alo, 512, 7, 3);
    {
        dim3 grid(768 / TN, N_PAD / TM);
        gemm_mfma_kernel<<<grid, 256, 0, stream>>>(Ahi, Alo, W2thi, W2tlo, b2, bufF,
                                                   N, 512, 768, 1);
    }
    // --- layer 3: gemm 768->8 -> agg8 (+b3) ---
    gemm_n8_kernel<<<N, 64, 0, stream>>>(bufF, W3, xw8, 768);
    agg8_kernel<<<N, 64, 0, stream>>>(xw8, col_ptr, csr_src, csr_w, dinv, b3, out);

    (void)out_size; (void)n_in; (void)in_sizes;
}